// Round 11
// baseline (162.452 us; speedup 1.0000x reference)
//
#include <hip/hip_runtime.h>

// Problem constants: B=8, N_IN=256, N=8192, D=64, K=512
#define NIN    256
#define NCOL   8192
#define DDIM   64
#define KCODES 512
#define NCTOT  65536                         // total columns = B*N
#define ZQ_ELEMS (8ull * 64ull * 8192ull)    // zq floats; hist follows

// ---------------------------------------------------------------------------
// K1 prep: Wt[i][d] = W[d][i] (conv s_loads contiguous); embT[d][k] =
// emb[k][d] (search s_loads contiguous in k); emb_sq[k] = ||emb[k]||^2
// (ascending-d, bit-exact vs all passing rounds); hist_out = ind_hist;
// cand[] = ~0 (u64 argmin accumulators; re-init every call).
// Grid 128 x 256 = 32768 threads; each inits 2 cand slots.
// ---------------------------------------------------------------------------
__global__ __launch_bounds__(256) void vq_prep(const float* __restrict__ W,
                                               const float* __restrict__ emb,
                                               const float* __restrict__ ind_hist,
                                               float* __restrict__ Wt,
                                               float* __restrict__ embT,
                                               float* __restrict__ emb_sq,
                                               unsigned long long* __restrict__ cand,
                                               float* __restrict__ hist_out)
{
    const int t = blockIdx.x * 256 + threadIdx.x;   // t < 32768
    cand[t]         = ~0ull;
    cand[t + 32768] = ~0ull;
    if (t < NIN * DDIM) {
        int i = t >> 6;
        int d = t & 63;
        Wt[t] = W[d * NIN + i];
    }
    {
        int d = t >> 9;          // 0..63
        int k = t & 511;         // 0..511
        embT[t] = emb[k * DDIM + d];
    }
    if (t < KCODES) {
        const float* __restrict__ ek = emb + t * DDIM;
        float s = 0.f;
        #pragma unroll
        for (int d = 0; d < DDIM; ++d) s = fmaf(ek[d], ek[d], s);
        emb_sq[t] = s;
        hist_out[t] = ind_hist[t];
    }
}

// ---------------------------------------------------------------------------
// K2 conv (round-4 verified): 1024 blocks x 256, (256,4) -> cap 128 VGPR.
// Wave w computes d-slice [16w,16w+16) for 64 cols (lane=col, Wt s_load,
// ascending-i fmaf — bit-identical ze). Writes ze to OUTPUT buffer in
// (b,d,n) layout, coalesced; vq_final overwrites with zq later.
// ---------------------------------------------------------------------------
__global__ __launch_bounds__(256, 4) void vq_conv(const float* __restrict__ z,
                                                  const float* __restrict__ Wt,
                                                  float* __restrict__ out)
{
    const int tid = threadIdx.x;
    const int cl  = tid & 63;
    const int w   = __builtin_amdgcn_readfirstlane(tid >> 6);
    const int C   = blockIdx.x * 64 + cl;
    const int b   = C >> 13;
    const int n   = C & (NCOL - 1);

    const float* __restrict__ zp = z + (size_t)b * NIN * NCOL + n;
    const float* __restrict__ wp = Wt + w * 16;

    float acc[16];
    #pragma unroll
    for (int j = 0; j < 16; ++j) acc[j] = 0.f;

    for (int i = 0; i < NIN; i += 4) {
        float z0 = zp[(size_t)(i + 0) * NCOL];
        float z1 = zp[(size_t)(i + 1) * NCOL];
        float z2 = zp[(size_t)(i + 2) * NCOL];
        float z3 = zp[(size_t)(i + 3) * NCOL];
        const float* __restrict__ w0 = wp + (size_t)(i + 0) * DDIM;  // s_load
        const float* __restrict__ w1 = wp + (size_t)(i + 1) * DDIM;
        const float* __restrict__ w2 = wp + (size_t)(i + 2) * DDIM;
        const float* __restrict__ w3 = wp + (size_t)(i + 3) * DDIM;
        #pragma unroll
        for (int j = 0; j < 16; ++j) {
            float a = acc[j];
            a = fmaf(w0[j], z0, a);   // ascending i: bit-exact
            a = fmaf(w1[j], z1, a);
            a = fmaf(w2[j], z2, a);
            a = fmaf(w3[j], z3, a);
            acc[j] = a;
        }
    }

    float* __restrict__ op = out + ((size_t)b * DDIM + w * 16) * NCOL + n;
    #pragma unroll
    for (int j = 0; j < 16; ++j) op[(size_t)j * NCOL] = acc[j];
}

// ---------------------------------------------------------------------------
// K3 search: 2048 blocks x 256, (256,4) -> cap 128 (round 9/10 lesson:
// cap 64 makes hipcc spill wholesale; round 8 shows this loop allocates at
// ~52 VGPR under cap 128, and <=64 VGPR lets HW run 8 waves/SIMD).
// 8 blocks/CU -> 32 waves/CU. Block = 64-col tile x k-half; wave w scans
// k in [256h + 64w, +64), k-tiled by 16:
//   per tile: 8 static d-chunks of 8: {8 ds_read_b32 -> zd[8], then 8x16
//   reg-reg FMAs; emb row = wave-uniform s_load of embT[d][kt..kt+16)}.
// All register-array indices compile-time constant (rule #20).
// Per-thread candidate -> packed u64 atomicMin (round-4 verified):
// hi = order-preserving dist bits, lo = k -> lexicographic min == first-min-k
// argmin; commutative -> deterministic.
// ---------------------------------------------------------------------------
__global__ __launch_bounds__(256, 4) void vq_search(const float* __restrict__ zeb,
                                                    const float* __restrict__ embT,
                                                    const float* __restrict__ emb_sq,
                                                    unsigned long long* __restrict__ cand)
{
    __shared__ float ze_lds[64][DDIM + 1];   // stride 65: b32 conflict-free

    const int tid = threadIdx.x;
    const int C0  = (blockIdx.x >> 1) * 64;
    const int h   = blockIdx.x & 1;
    const int b   = C0 >> 13;                // 64-col tile never crosses b
    const int n0  = C0 & (NCOL - 1);

    // coop load ze tile from out buffer (round-4 verified pattern)
    {
        const int r  = tid >> 2;
        const int cc = (tid & 3) * 16;
        const float4* __restrict__ src = reinterpret_cast<const float4*>(
            zeb + ((size_t)b * DDIM + r) * NCOL + n0 + cc);
        #pragma unroll
        for (int v = 0; v < 4; ++v) {
            float4 x = src[v];
            ze_lds[cc + 4 * v + 0][r] = x.x;
            ze_lds[cc + 4 * v + 1][r] = x.y;
            ze_lds[cc + 4 * v + 2][r] = x.z;
            ze_lds[cc + 4 * v + 3][r] = x.w;
        }
    }
    __syncthreads();

    const int cl = tid & 63;
    const int w  = __builtin_amdgcn_readfirstlane(tid >> 6);

    // zesq: ascending-d chain (bit-exact)
    float zesq = 0.f;
    #pragma unroll
    for (int d = 0; d < DDIM; ++d) {
        float zd = ze_lds[cl][d];
        zesq = fmaf(zd, zd, zesq);
    }

    // wave w owns k in [256h + 64w, +64)
    const int k0 = h * (KCODES / 2) + w * 64;
    float best  = 3.4e38f;
    int   bestk = k0;

    for (int t4 = 0; t4 < 4; ++t4) {                  // 4 k-tiles of 16
        const int kt = k0 + t4 * 16;

        float acc[16];
        #pragma unroll
        for (int kk = 0; kk < 16; ++kk) acc[kk] = 0.f;

        #pragma unroll
        for (int dc = 0; dc < 8; ++dc) {              // 8 static d-chunks of 8
            float zd[8];
            #pragma unroll
            for (int j = 0; j < 8; ++j)
                zd[j] = ze_lds[cl][dc * 8 + j];       // static idx: VGPR

            #pragma unroll
            for (int j = 0; j < 8; ++j) {
                const float* __restrict__ ep =
                    embT + (size_t)(dc * 8 + j) * KCODES + kt;  // s_load x16
                #pragma unroll
                for (int kk = 0; kk < 16; ++kk)
                    acc[kk] = fmaf(ep[kk], zd[j], acc[kk]);  // ascending d
            }
        }

        #pragma unroll
        for (int kk = 0; kk < 16; ++kk) {
            const int k = kt + kk;
            float dist = (zesq + emb_sq[k]) - 2.0f * acc[kk];  // ref order
            if (dist < best) { best = dist; bestk = k; }       // first-min
        }
    }

    unsigned u   = __float_as_uint(best);
    unsigned enc = u ^ ((unsigned)((int)u >> 31) | 0x80000000u);  // order-map
    unsigned long long pk =
        ((unsigned long long)enc << 32) | (unsigned)bestk;
    atomicMin(&cand[C0 + cl], pk);
}

// ---------------------------------------------------------------------------
// K4 final (round-4 verified): 1024 blocks x 256. Re-stage ze tile, read the
// winning (dist,k), write zq = ze + (emb[k]-ze) coalesced, 1 hist atomic/col.
// ---------------------------------------------------------------------------
__global__ __launch_bounds__(256, 4) void vq_final(const float* __restrict__ emb,
                                                   const unsigned long long* __restrict__ cand,
                                                   float* __restrict__ out,
                                                   float* __restrict__ hist)
{
    __shared__ float ze_lds[64][DDIM + 1];

    const int tid = threadIdx.x;
    const int C0  = blockIdx.x * 64;
    const int b   = C0 >> 13;
    const int n0  = C0 & (NCOL - 1);

    {
        const int r  = tid >> 2;
        const int cc = (tid & 3) * 16;
        const float4* __restrict__ src = reinterpret_cast<const float4*>(
            out + ((size_t)b * DDIM + r) * NCOL + n0 + cc);
        #pragma unroll
        for (int v = 0; v < 4; ++v) {
            float4 x = src[v];
            ze_lds[cc + 4 * v + 0][r] = x.x;
            ze_lds[cc + 4 * v + 1][r] = x.y;
            ze_lds[cc + 4 * v + 2][r] = x.z;
            ze_lds[cc + 4 * v + 3][r] = x.w;
        }
    }
    __syncthreads();

    const int cl = tid & 63;
    const int w  = __builtin_amdgcn_readfirstlane(tid >> 6);
    const int C  = C0 + cl;
    const int n  = n0 + cl;

    const int fk = (int)(unsigned)cand[C];
    if (w == 0) atomicAdd(hist + fk, 1.0f);

    const float4* __restrict__ eb =
        reinterpret_cast<const float4*>(emb + (size_t)fk * DDIM) + w * 4;
    float* __restrict__ op = out + ((size_t)b * DDIM + w * 16) * NCOL + n;
    #pragma unroll
    for (int v = 0; v < 4; ++v) {
        float4 e = eb[v];
        float z0 = ze_lds[cl][w * 16 + 4 * v + 0];
        float z1 = ze_lds[cl][w * 16 + 4 * v + 1];
        float z2 = ze_lds[cl][w * 16 + 4 * v + 2];
        float z3 = ze_lds[cl][w * 16 + 4 * v + 3];
        op[(size_t)(4 * v + 0) * NCOL] = z0 + (e.x - z0);
        op[(size_t)(4 * v + 1) * NCOL] = z1 + (e.y - z1);
        op[(size_t)(4 * v + 2) * NCOL] = z2 + (e.z - z2);
        op[(size_t)(4 * v + 3) * NCOL] = z3 + (e.w - z3);
    }
}

// ---------------------------------------------------------------------------
extern "C" void kernel_launch(void* const* d_in, const int* in_sizes, int n_in,
                              void* d_out, int out_size, void* d_ws, size_t ws_size,
                              hipStream_t stream)
{
    const float* z        = (const float*)d_in[0];  // (8, 256, 8192)
    const float* W        = (const float*)d_in[1];  // (64, 256)
    const float* emb      = (const float*)d_in[2];  // (512, 64)
    const float* ind_hist = (const float*)d_in[3];  // (512,)

    float* out  = (float*)d_out;                    // zq then hist
    float* hist = out + ZQ_ELEMS;

    unsigned long long* cand = (unsigned long long*)d_ws;          // 512 KB
    float* Wt     = (float*)((char*)d_ws + NCTOT * 8);             // 64 KB
    float* embT   = Wt + NIN * DDIM;                               // 128 KB
    float* emb_sq = embT + DDIM * KCODES;                          // 2 KB

    hipLaunchKernelGGL(vq_prep, dim3(128), dim3(256), 0, stream,
                       W, emb, ind_hist, Wt, embT, emb_sq, cand, hist);

    hipLaunchKernelGGL(vq_conv, dim3(1024), dim3(256), 0, stream,
                       z, Wt, out);

    // 64-col tile x k-half -> 2048 blocks = 8 blocks/CU = 32 waves/CU
    hipLaunchKernelGGL(vq_search, dim3(2048), dim3(256), 0, stream,
                       out, embT, emb_sq, cand);

    hipLaunchKernelGGL(vq_final, dim3(1024), dim3(256), 0, stream,
                       emb, cand, out, hist);
}

// Round 12
// 134.733 us; speedup vs baseline: 1.2057x; 1.2057x over previous
//
#include <hip/hip_runtime.h>

// Problem constants: B=8, N_IN=256, N=8192, D=64, K=512
#define NIN    256
#define NCOL   8192
#define DDIM   64
#define KCODES 512
#define ZQ_ELEMS (8ull * 64ull * 8192ull)    // zq floats; hist follows

// ---------------------------------------------------------------------------
// Prep: Wt[i][d] = W[d][i] (conv s_loads contiguous); embT[d][k] = emb[k][d]
// (search s_loads contiguous in k); emb_sq[k] = ||emb[k]||^2 (ascending-d,
// bit-exact vs all passing rounds); hist_out = ind_hist (re-init every call).
// ---------------------------------------------------------------------------
__global__ __launch_bounds__(256) void vq_prep(const float* __restrict__ W,
                                               const float* __restrict__ emb,
                                               const float* __restrict__ ind_hist,
                                               float* __restrict__ Wt,
                                               float* __restrict__ embT,
                                               float* __restrict__ emb_sq,
                                               float* __restrict__ hist_out)
{
    const int t = blockIdx.x * 256 + threadIdx.x;   // t < 32768
    if (t < NIN * DDIM) {
        int i = t >> 6;
        int d = t & 63;
        Wt[t] = W[d * NIN + i];
    }
    {
        int d = t >> 9;          // 0..63
        int k = t & 511;         // 0..511
        embT[t] = emb[k * DDIM + d];
    }
    if (t < KCODES) {
        const float* __restrict__ ek = emb + t * DDIM;
        float s = 0.f;
        #pragma unroll
        for (int d = 0; d < DDIM; ++d) s = fmaf(ek[d], ek[d], s);
        emb_sq[t] = s;
        hist_out[t] = ind_hist[t];
    }
}

// ---------------------------------------------------------------------------
// Main fused kernel: block (256 thr / 4 waves) owns 64 columns; 1024 blocks.
//  conv   : wave w -> d-slice [16w,16w+16) for 64 cols (lane=col, Wt s_load,
//           ascending-i fmaf — bit-identical to all passing rounds). Stores
//           to LDS transpose tile (stride 65: b32 conflict-free).
//  ze->reg: each thread loads its column's FULL ze[64] into VGPRs with 64
//           scalar ds_reads, ONE lgkmcnt(0), then never touches LDS in the
//           hot loop. d-indices are all compile-time constants (rule #20:
//           round 7's runtime-indexed ze[] went to scratch; round 8 proved
//           static-index arrays allocate cleanly). Live set ~100 < cap 128.
//  search : wave w owns k-quarter [128w,128w+128), 8 rolled tiles of 16.
//           Per tile: 64 fully-unrolled j-steps: {wave-uniform s_load of
//           embT[j][kt..kt+16) -> 16 reg-reg FMAs}. ZERO ds_read in the
//           k-loop -> the lgkm queue is SMEM-only, so the compiler can use
//           counted lgkmcnt waits instead of the ds/smem mixed-queue full
//           drain that capped rounds 4-11 at ~2.5x the FMA floor.
//           dist = (zesq + emb_sq[k]) - 2*cr, ascending-d cr: bit-exact.
//  merge  : 4 per-wave candidates via LDS, ascending-w strict-< scan
//           == jnp.argmin first-min tie-break.
//  epilog : wave w writes zq d-slice [16w,16w+16); 1 hist atomic per column.
// ---------------------------------------------------------------------------
__global__ __launch_bounds__(256, 4) void vq_main(const float* __restrict__ z,
                                                  const float* __restrict__ Wt,
                                                  const float* __restrict__ emb,
                                                  const float* __restrict__ embT,
                                                  const float* __restrict__ emb_sq,
                                                  float* __restrict__ out,
                                                  float* __restrict__ hist)
{
    __shared__ float ze_lds[64][DDIM + 1];   // stride 65: b32 conflict-free
    __shared__ float bw_lds[4][64];
    __shared__ int   bk_lds[4][64];

    const int tid = threadIdx.x;
    const int cl  = tid & 63;                                   // column (lane)
    const int w   = __builtin_amdgcn_readfirstlane(tid >> 6);   // wave id 0..3
    const int C   = blockIdx.x * 64 + cl;
    const int b   = C >> 13;
    const int n   = C & (NCOL - 1);

    // ---------------- conv phase (verified) --------------------------------
    {
        const float* __restrict__ zp = z + (size_t)b * NIN * NCOL + n;
        const float* __restrict__ wp = Wt + w * 16;

        float acc[16];
        #pragma unroll
        for (int j = 0; j < 16; ++j) acc[j] = 0.f;

        for (int i = 0; i < NIN; i += 4) {
            float z0 = zp[(size_t)(i + 0) * NCOL];
            float z1 = zp[(size_t)(i + 1) * NCOL];
            float z2 = zp[(size_t)(i + 2) * NCOL];
            float z3 = zp[(size_t)(i + 3) * NCOL];
            const float* __restrict__ w0 = wp + (size_t)(i + 0) * DDIM;  // s_load
            const float* __restrict__ w1 = wp + (size_t)(i + 1) * DDIM;
            const float* __restrict__ w2 = wp + (size_t)(i + 2) * DDIM;
            const float* __restrict__ w3 = wp + (size_t)(i + 3) * DDIM;
            #pragma unroll
            for (int j = 0; j < 16; ++j) {
                float a = acc[j];
                a = fmaf(w0[j], z0, a);   // ascending i: bit-exact
                a = fmaf(w1[j], z1, a);
                a = fmaf(w2[j], z2, a);
                a = fmaf(w3[j], z3, a);
                acc[j] = a;
            }
        }
        #pragma unroll
        for (int j = 0; j < 16; ++j) ze_lds[cl][w * 16 + j] = acc[j];
    }
    __syncthreads();

    // ---------------- ze -> registers, ALL static indices ------------------
    float ze[DDIM];
    #pragma unroll
    for (int j = 0; j < DDIM; ++j) ze[j] = ze_lds[cl][j];   // 64 ds_read_b32

    // ---------------- zesq: ascending-d chain (bit-exact) ------------------
    float zesq = 0.f;
    #pragma unroll
    for (int d = 0; d < DDIM; ++d) zesq = fmaf(ze[d], ze[d], zesq);

    // ---------------- search: wave w owns k in [128w, 128w+128) ------------
    const int k0 = w * (KCODES / 4);
    float best  = 3.4e38f;
    int   bestk = k0;

    #pragma unroll 1
    for (int t8 = 0; t8 < 8; ++t8) {                  // 8 rolled tiles of 16
        const int kt = k0 + t8 * 16;
        const float* __restrict__ ep0 = embT + kt;    // wave-uniform base

        float acc[16];
        #pragma unroll
        for (int kk = 0; kk < 16; ++kk) acc[kk] = 0.f;

        #pragma unroll
        for (int j = 0; j < DDIM; ++j) {              // fully unrolled: static
            const float* __restrict__ ep = ep0 + (size_t)j * KCODES;  // s_load
            const float zj = ze[j];                   // constant index: VGPR
            #pragma unroll
            for (int kk = 0; kk < 16; ++kk)
                acc[kk] = fmaf(ep[kk], zj, acc[kk]);  // ascending d per (c,k)
        }

        #pragma unroll
        for (int kk = 0; kk < 16; ++kk) {
            const int k = kt + kk;
            float dist = (zesq + emb_sq[k]) - 2.0f * acc[kk];  // ref order
            if (dist < best) { best = dist; bestk = k; }       // first-min
        }
    }
    bw_lds[w][cl] = best;
    bk_lds[w][cl] = bestk;
    __syncthreads();

    // ---------------- merge 4 candidates (ascending w, strict <) -----------
    float fb = bw_lds[0][cl];
    int   fk = bk_lds[0][cl];
    #pragma unroll
    for (int ww = 1; ww < 4; ++ww) {
        float v = bw_lds[ww][cl];
        int  kv = bk_lds[ww][cl];
        if (v < fb) { fb = v; fk = kv; }
    }

    // ---------------- histogram: one atomic per column ---------------------
    if (w == 0) atomicAdd(hist + fk, 1.0f);

    // ---------------- straight-through output: wave w writes [16w,16w+16) --
    const float4* __restrict__ eb =
        reinterpret_cast<const float4*>(emb + (size_t)fk * DDIM) + w * 4;
    float* __restrict__ op = out + ((size_t)b * DDIM + w * 16) * NCOL + n;
    #pragma unroll
    for (int v = 0; v < 4; ++v) {
        float4 e = eb[v];
        float z0 = ze_lds[cl][w * 16 + 4 * v + 0];   // LDS: static indices
        float z1 = ze_lds[cl][w * 16 + 4 * v + 1];
        float z2 = ze_lds[cl][w * 16 + 4 * v + 2];
        float z3 = ze_lds[cl][w * 16 + 4 * v + 3];
        op[(size_t)(4 * v + 0) * NCOL] = z0 + (e.x - z0);
        op[(size_t)(4 * v + 1) * NCOL] = z1 + (e.y - z1);
        op[(size_t)(4 * v + 2) * NCOL] = z2 + (e.z - z2);
        op[(size_t)(4 * v + 3) * NCOL] = z3 + (e.w - z3);
    }
}

// ---------------------------------------------------------------------------
extern "C" void kernel_launch(void* const* d_in, const int* in_sizes, int n_in,
                              void* d_out, int out_size, void* d_ws, size_t ws_size,
                              hipStream_t stream)
{
    const float* z        = (const float*)d_in[0];  // (8, 256, 8192)
    const float* W        = (const float*)d_in[1];  // (64, 256)
    const float* emb      = (const float*)d_in[2];  // (512, 64)
    const float* ind_hist = (const float*)d_in[3];  // (512,)

    float* out  = (float*)d_out;                    // zq then hist
    float* hist = out + ZQ_ELEMS;

    float* Wt     = (float*)d_ws;                   // 16384 floats
    float* embT   = Wt + NIN * DDIM;                // 32768 floats
    float* emb_sq = embT + DDIM * KCODES;           // 512 floats

    hipLaunchKernelGGL(vq_prep, dim3(128), dim3(256), 0, stream,
                       W, emb, ind_hist, Wt, embT, emb_sq, hist);

    // 64 columns per block -> 1024 blocks of 256 (4 blocks/CU, 16 waves/CU)
    hipLaunchKernelGGL(vq_main, dim3(1024), dim3(256), 0, stream,
                       z, Wt, emb, embT, emb_sq, out, hist);
}